// Round 13
// baseline (424.353 us; speedup 1.0000x reference)
//
#include <hip/hip_runtime.h>
#include <hip/hip_bf16.h>
#include <math.h>

#define Bc 2
#define Lc 2048
#define Mc 2048
#define Dc 1024
#define Hc 16
#define FFc 4096
#define DHc 64

typedef __bf16 bf16;
typedef float f32x4 __attribute__((ext_vector_type(4)));
typedef __bf16 bf16x8 __attribute__((ext_vector_type(8)));
typedef __bf16 bf16x4 __attribute__((ext_vector_type(4)));
typedef __bf16 bf16x2 __attribute__((ext_vector_type(2)));

struct Ptrs8 { const float* p[8]; };

__device__ inline void gload16(const bf16* g, const bf16* lds_base) {
  __builtin_amdgcn_global_load_lds(
      (const __attribute__((address_space(1))) void*)g,
      (__attribute__((address_space(3))) void*)lds_base, 16, 0, 0);
}

#define WAIT_VM(n) asm volatile("s_waitcnt vmcnt(" #n ")" ::: "memory")
#define WAIT_LGKM(n) asm volatile("s_waitcnt lgkmcnt(" #n ")" ::: "memory")
#define RAW_BAR() __builtin_amdgcn_s_barrier()
#define SCHED_FENCE() __builtin_amdgcn_sched_barrier(0)

__device__ inline float gelu_f(float v) {
  float u = 0.7978845608f * (v + 0.044715f * v * v * v);
  float e = exp2f(u * 2.885390082f);  // exp(2u)
  float th = 1.0f - 2.0f / (e + 1.0f);
  return 0.5f * v * (1.0f + th);
}

// XCD-aware bijective remap of flat block id (requires nwg % 8 == 0)
__device__ inline int xcd_remap(int flat, int nwg) {
  int cpx = nwg >> 3;
  return (flat & 7) * cpx + (flat >> 3);
}

// ---------------- fp32 -> bf16 convert (vectorized) ----------------
__global__ __launch_bounds__(256) void k_f2b(const float* __restrict__ in,
                                             bf16* __restrict__ out, long n4) {
  long i = (long)blockIdx.x * 256 + threadIdx.x;
  if (i >= n4) return;
  f32x4 v = *(const f32x4*)(in + i * 4);
  bf16x4 o;
  o[0] = (bf16)v[0]; o[1] = (bf16)v[1]; o[2] = (bf16)v[2]; o[3] = (bf16)v[3];
  *(bf16x4*)(out + i * 4) = o;
}

// ------- batched weight transpose (8x DxD): out[z][n*K+k] = bf16(in_z[k*N+n])
__global__ __launch_bounds__(256) void k_transpose_w8(Ptrs8 srcs,
                                                      bf16* __restrict__ out) {
  __shared__ float tile[64][65];
  const float* in = srcs.p[blockIdx.z];
  bf16* o = out + (long)blockIdx.z * Dc * Dc;
  int n0 = blockIdx.x * 64, k0 = blockIdx.y * 64;
  int t = threadIdx.x;
  int tr = t >> 4, tc = (t & 15) * 4;
#pragma unroll
  for (int p = 0; p < 4; p++) {
    int r = p * 16 + tr;
    f32x4 v = *(const f32x4*)(in + (long)(k0 + r) * Dc + n0 + tc);
    tile[r][tc] = v[0]; tile[r][tc + 1] = v[1];
    tile[r][tc + 2] = v[2]; tile[r][tc + 3] = v[3];
  }
  __syncthreads();
#pragma unroll
  for (int p = 0; p < 4; p++) {
    int rn = p * 16 + tr;
    bf16x4 ov;
    ov[0] = (bf16)tile[tc + 0][rn]; ov[1] = (bf16)tile[tc + 1][rn];
    ov[2] = (bf16)tile[tc + 2][rn]; ov[3] = (bf16)tile[tc + 3][rn];
    *(bf16x4*)(o + (long)(n0 + rn) * Dc + k0 + tc) = ov;
  }
}

// ---------------- weight transpose+convert: out[n*K+k] = bf16(in[k*N+n]) ----
__global__ __launch_bounds__(256) void k_transpose_w(const float* __restrict__ in,
                                                     bf16* __restrict__ out,
                                                     int K, int N) {
  __shared__ float tile[64][65];
  int n0 = blockIdx.x * 64, k0 = blockIdx.y * 64;
  int t = threadIdx.x;
  int tr = t >> 4, tc = (t & 15) * 4;
#pragma unroll
  for (int p = 0; p < 4; p++) {
    int r = p * 16 + tr;
    f32x4 v = *(const f32x4*)(in + (long)(k0 + r) * N + n0 + tc);
    tile[r][tc] = v[0]; tile[r][tc + 1] = v[1];
    tile[r][tc + 2] = v[2]; tile[r][tc + 3] = v[3];
  }
  __syncthreads();
#pragma unroll
  for (int p = 0; p < 4; p++) {
    int rn = p * 16 + tr;
    bf16x4 o;
    o[0] = (bf16)tile[tc + 0][rn]; o[1] = (bf16)tile[tc + 1][rn];
    o[2] = (bf16)tile[tc + 2][rn]; o[3] = (bf16)tile[tc + 3][rn];
    *(bf16x4*)(out + (long)(n0 + rn) * K + k0 + tc) = o;
  }
}

// ---- V transpose: vt[(b*H+h)*DH+d][j] = vb[b][j][h*DH+d], j in [0,N) ------
__global__ __launch_bounds__(256) void k_transpose_v(const bf16* __restrict__ vb,
                                                     bf16* __restrict__ vt, int N) {
  __shared__ bf16 tile[64][72];
  int j0 = blockIdx.x * 64;
  int bh = blockIdx.y; int b = bh >> 4; int h = bh & 15;
  int t = threadIdx.x;
#pragma unroll
  for (int c = 0; c < 2; c++) {
    int id = t + c * 256;
    int r = id >> 3, c8 = (id & 7) * 8;
    *(bf16x8*)&tile[r][c8] =
        *(const bf16x8*)(vb + ((long)(b * N + j0 + r)) * Dc + h * DHc + c8);
  }
  __syncthreads();
#pragma unroll
  for (int c = 0; c < 2; c++) {
    int id = t + c * 256;
    int d = id >> 3, j8 = (id & 7) * 8;
    bf16x8 o;
#pragma unroll
    for (int e = 0; e < 8; e++) o[e] = tile[j8 + e][d];
    *(bf16x8*)(vt + ((long)bh * DHc + d) * N + j0 + j8) = o;
  }
}

// ------- 128x128 MFMA GEMM, BK=64, dbuf + counted vmcnt (R8 proven) --------
__global__ __launch_bounds__(256) void k_gemm128(
    const bf16* __restrict__ A0, const bf16* __restrict__ A1,
    const bf16* __restrict__ A2, long lda,
    const bf16* __restrict__ B0, long bstride,
    bf16* __restrict__ outB, long ldc, long cstride,
    const float* __restrict__ bias0, const float* __restrict__ bias1,
    const float* __restrict__ bias2, int Kdim, int act, float scale0) {
  __shared__ __align__(16) bf16 As[2][128 * 64];
  __shared__ __align__(16) bf16 Bs[2][128 * 64];
  int gx = gridDim.x, gy = gridDim.y;
  int nwg = gx * gy * gridDim.z;
  int flat = (blockIdx.z * gy + blockIdx.y) * gx + blockIdx.x;
  int f2 = xcd_remap(flat, nwg);
  int bxi = f2 % gx; int tmp = f2 / gx;
  int byi = tmp % gy; int z = tmp / gy;
  const bf16* A = (z == 0) ? A0 : ((z == 1) ? A1 : A2);
  const bf16* Bt = B0 + (long)z * bstride;
  const float* bias = (z == 0) ? bias0 : ((z == 1) ? bias1 : bias2);
  float scl = (z == 0) ? scale0 : 1.0f;
  long cbase = (long)z * cstride;
  int bm = byi * 128, bn = bxi * 128;
  int t = threadIdx.x, w = t >> 6, lane = t & 63;
  int wm = w >> 1, wn = w & 1;
  int lr = lane & 15, lg = lane >> 4;
  int srow = lane >> 3;
  int scol = (((lane & 7) * 16) ^ ((lane >> 3) << 4)) >> 1;  // pre-swizzled src
  f32x4 acc[4][4] = {};
  int nk = Kdim >> 6;
  auto stage = [&](int buf, int kt2) {
    long k0 = (long)kt2 * 64;
#pragma unroll
    for (int i = 0; i < 4; i++) {
      int row = (i * 4 + w) * 8 + srow;
      gload16(A + (long)(bm + row) * lda + k0 + scol, &As[buf][(i * 4 + w) * 512]);
      gload16(Bt + (long)(bn + row) * Kdim + k0 + scol, &Bs[buf][(i * 4 + w) * 512]);
    }
  };
  stage(0, 0);
  if (nk > 1) stage(1, 1);
  for (int kt = 0; kt < nk; ++kt) {
    int cur = kt & 1;
    if (kt + 1 < nk) { WAIT_VM(8); } else { WAIT_VM(0); }
    RAW_BAR();
    SCHED_FENCE();
    const char* pa = (const char*)&As[cur][0];
    const char* pb = (const char*)&Bs[cur][0];
    int xr = (lr & 7) << 4;
    bf16x8 af[2][4], bfr[2][4];
#pragma unroll
    for (int m = 0; m < 4; m++) {
      int row = wm * 64 + m * 16 + lr;
      af[0][m] = *(const bf16x8*)(pa + (row << 7) + ((lg * 16) ^ xr));
    }
#pragma unroll
    for (int n = 0; n < 4; n++) {
      int row = wn * 64 + n * 16 + lr;
      bfr[0][n] = *(const bf16x8*)(pb + (row << 7) + ((lg * 16) ^ xr));
    }
    SCHED_FENCE();
#pragma unroll
    for (int m = 0; m < 4; m++) {
      int row = wm * 64 + m * 16 + lr;
      af[1][m] = *(const bf16x8*)(pa + (row << 7) + ((64 + lg * 16) ^ xr));
    }
#pragma unroll
    for (int n = 0; n < 4; n++) {
      int row = wn * 64 + n * 16 + lr;
      bfr[1][n] = *(const bf16x8*)(pb + (row << 7) + ((64 + lg * 16) ^ xr));
    }
    SCHED_FENCE();
    WAIT_LGKM(8);
    SCHED_FENCE();
#pragma unroll
    for (int m = 0; m < 4; m++)
#pragma unroll
      for (int n = 0; n < 4; n++)
        acc[m][n] = __builtin_amdgcn_mfma_f32_16x16x32_bf16(af[0][m], bfr[0][n],
                                                            acc[m][n], 0, 0, 0);
    WAIT_LGKM(0);
    SCHED_FENCE();
    RAW_BAR();
    if (kt + 2 < nk) stage(cur, kt + 2);
    SCHED_FENCE();
#pragma unroll
    for (int m = 0; m < 4; m++)
#pragma unroll
      for (int n = 0; n < 4; n++)
        acc[m][n] = __builtin_amdgcn_mfma_f32_16x16x32_bf16(af[1][m], bfr[1][n],
                                                            acc[m][n], 0, 0, 0);
  }
#pragma unroll
  for (int n = 0; n < 4; n++) {
    int cg = bn + wn * 64 + n * 16 + lr;
    float bv = bias ? bias[cg] : 0.0f;
#pragma unroll
    for (int m = 0; m < 4; m++) {
#pragma unroll
      for (int rr = 0; rr < 4; rr++) {
        int rg = bm + wm * 64 + m * 16 + lg * 4 + rr;
        float v = (acc[m][n][rr] + bv) * scl;
        if (act == 1) v = gelu_f(v);
        outB[cbase + (long)rg * ldc + cg] = (bf16)v;
      }
    }
  }
}

// ------- split-K GEMM -> bf16 partial slabs (R8 proven) --------------------
__global__ __launch_bounds__(256) void k_gemmsk(
    const bf16* __restrict__ A, long lda,
    const bf16* __restrict__ Bt, int Kfull,
    bf16* __restrict__ psum, long slab, int Kchunk, int ldc) {
  __shared__ __align__(16) bf16 As[2][128 * 64];
  __shared__ __align__(16) bf16 Bs[2][128 * 64];
  int gx = gridDim.x, gy = gridDim.y;
  int nwg = gx * gy * gridDim.z;
  int flat = (blockIdx.z * gy + blockIdx.y) * gx + blockIdx.x;
  int f2 = xcd_remap(flat, nwg);
  int bxi = f2 % gx; int tmp = f2 / gx;
  int byi = tmp % gy; int z = tmp / gy;
  int bm = byi * 128, bn = bxi * 128;
  int t = threadIdx.x, w = t >> 6, lane = t & 63;
  int wm = w >> 1, wn = w & 1;
  int lr = lane & 15, lg = lane >> 4;
  int srow = lane >> 3;
  int scol = (((lane & 7) * 16) ^ ((lane >> 3) << 4)) >> 1;
  f32x4 acc[4][4] = {};
  int nk = Kchunk >> 6;
  long kstart = (long)z * Kchunk;
  auto stage = [&](int buf, int kt2) {
    long k0 = kstart + (long)kt2 * 64;
#pragma unroll
    for (int i = 0; i < 4; i++) {
      int row = (i * 4 + w) * 8 + srow;
      gload16(A + (long)(bm + row) * lda + k0 + scol, &As[buf][(i * 4 + w) * 512]);
      gload16(Bt + (long)(bn + row) * Kfull + k0 + scol, &Bs[buf][(i * 4 + w) * 512]);
    }
  };
  stage(0, 0);
  if (nk > 1) stage(1, 1);
  for (int kt = 0; kt < nk; ++kt) {
    int cur = kt & 1;
    if (kt + 1 < nk) { WAIT_VM(8); } else { WAIT_VM(0); }
    RAW_BAR();
    SCHED_FENCE();
    const char* pa = (const char*)&As[cur][0];
    const char* pb = (const char*)&Bs[cur][0];
    int xr = (lr & 7) << 4;
    bf16x8 af[2][4], bfr[2][4];
#pragma unroll
    for (int m = 0; m < 4; m++) {
      int row = wm * 64 + m * 16 + lr;
      af[0][m] = *(const bf16x8*)(pa + (row << 7) + ((lg * 16) ^ xr));
    }
#pragma unroll
    for (int n = 0; n < 4; n++) {
      int row = wn * 64 + n * 16 + lr;
      bfr[0][n] = *(const bf16x8*)(pb + (row << 7) + ((lg * 16) ^ xr));
    }
    SCHED_FENCE();
#pragma unroll
    for (int m = 0; m < 4; m++) {
      int row = wm * 64 + m * 16 + lr;
      af[1][m] = *(const bf16x8*)(pa + (row << 7) + ((64 + lg * 16) ^ xr));
    }
#pragma unroll
    for (int n = 0; n < 4; n++) {
      int row = wn * 64 + n * 16 + lr;
      bfr[1][n] = *(const bf16x8*)(pb + (row << 7) + ((64 + lg * 16) ^ xr));
    }
    SCHED_FENCE();
    WAIT_LGKM(8);
    SCHED_FENCE();
#pragma unroll
    for (int m = 0; m < 4; m++)
#pragma unroll
      for (int n = 0; n < 4; n++)
        acc[m][n] = __builtin_amdgcn_mfma_f32_16x16x32_bf16(af[0][m], bfr[0][n],
                                                            acc[m][n], 0, 0, 0);
    WAIT_LGKM(0);
    SCHED_FENCE();
    RAW_BAR();
    if (kt + 2 < nk) stage(cur, kt + 2);
    SCHED_FENCE();
#pragma unroll
    for (int m = 0; m < 4; m++)
#pragma unroll
      for (int n = 0; n < 4; n++)
        acc[m][n] = __builtin_amdgcn_mfma_f32_16x16x32_bf16(af[1][m], bfr[1][n],
                                                            acc[m][n], 0, 0, 0);
  }
  bf16* po = psum + (long)z * slab;
#pragma unroll
  for (int n = 0; n < 4; n++) {
    int cg = bn + wn * 64 + n * 16 + lr;
#pragma unroll
    for (int m = 0; m < 4; m++) {
#pragma unroll
      for (int rr = 0; rr < 4; rr++) {
        int rg = bm + wm * 64 + m * 16 + lg * 4 + rr;
        po[(long)rg * ldc + cg] = (bf16)acc[m][n][rr];
      }
    }
  }
}

// ------- 256x256 MFMA GEMM, 512 thr / 8 waves, BK=64, dbuf counted vmcnt ---
// For 1-block/CU grids (FFN1, FFN2 split-K). bias==nullptr -> raw bf16 slab.
__global__ __launch_bounds__(512, 2) void k_gemm256(
    const bf16* __restrict__ A, long lda,
    const bf16* __restrict__ Bt, long ldb,
    bf16* __restrict__ outB, long ldc, long cstride,
    const float* __restrict__ bias, int Kchunk, int act) {
  __shared__ __align__(16) bf16 As[2][256 * 64];  // 64 KB
  __shared__ __align__(16) bf16 Bs[2][256 * 64];  // 64 KB
  int gx = gridDim.x, gy = gridDim.y;
  int nwg = gx * gy * gridDim.z;
  int flat = (blockIdx.z * gy + blockIdx.y) * gx + blockIdx.x;
  int f2 = xcd_remap(flat, nwg);
  int bxi = f2 % gx; int tmp = f2 / gx;
  int byi = tmp % gy; int z = tmp / gy;
  int bm = byi * 256, bn = bxi * 256;
  long kstart = (long)z * Kchunk;
  long cbase = (long)z * cstride;
  int t = threadIdx.x, w = t >> 6, lane = t & 63;
  int wm = w >> 2, wn = w & 3;            // 2 x 4 wave grid
  int lr = lane & 15, lg = lane >> 4;
  int srow = lane >> 3;
  int scol = (((lane & 7) * 16) ^ ((lane >> 3) << 4)) >> 1;  // pre-swizzled src
  f32x4 acc[8][4] = {};
  int nk = Kchunk >> 6;
  auto stage = [&](int buf, int kt2) {
    long k0 = kstart + (long)kt2 * 64;
#pragma unroll
    for (int i = 0; i < 4; i++) {
      int row = (i * 8 + w) * 8 + srow;   // rows 0..255
      gload16(A + (long)(bm + row) * lda + k0 + scol, &As[buf][(i * 8 + w) * 512]);
      gload16(Bt + (long)(bn + row) * ldb + k0 + scol, &Bs[buf][(i * 8 + w) * 512]);
    }
  };
  stage(0, 0);
  if (nk > 1) stage(1, 1);
  for (int kt = 0; kt < nk; ++kt) {
    int cur = kt & 1;
    if (kt + 1 < nk) { WAIT_VM(8); } else { WAIT_VM(0); }
    RAW_BAR();
    SCHED_FENCE();
    const char* pa = (const char*)&As[cur][0];
    const char* pb = (const char*)&Bs[cur][0];
    int xr = (lr & 7) << 4;
    // kk = 0
    {
      bf16x8 af[8], bfr[4];
#pragma unroll
      for (int m = 0; m < 8; m++) {
        int row = wm * 128 + m * 16 + lr;
        af[m] = *(const bf16x8*)(pa + (row << 7) + ((lg * 16) ^ xr));
      }
#pragma unroll
      for (int n = 0; n < 4; n++) {
        int row = wn * 64 + n * 16 + lr;
        bfr[n] = *(const bf16x8*)(pb + (row << 7) + ((lg * 16) ^ xr));
      }
      WAIT_LGKM(0);
      SCHED_FENCE();
#pragma unroll
      for (int m = 0; m < 8; m++)
#pragma unroll
        for (int n = 0; n < 4; n++)
          acc[m][n] = __builtin_amdgcn_mfma_f32_16x16x32_bf16(af[m], bfr[n],
                                                              acc[m][n], 0, 0, 0);
    }
    // kk = 1
    {
      bf16x8 af[8], bfr[4];
#pragma unroll
      for (int m = 0; m < 8; m++) {
        int row = wm * 128 + m * 16 + lr;
        af[m] = *(const bf16x8*)(pa + (row << 7) + ((64 + lg * 16) ^ xr));
      }
#pragma unroll
      for (int n = 0; n < 4; n++) {
        int row = wn * 64 + n * 16 + lr;
        bfr[n] = *(const bf16x8*)(pb + (row << 7) + ((64 + lg * 16) ^ xr));
      }
      WAIT_LGKM(0);
      SCHED_FENCE();
      RAW_BAR();
      if (kt + 2 < nk) stage(cur, kt + 2);
      SCHED_FENCE();
#pragma unroll
      for (int m = 0; m < 8; m++)
#pragma unroll
        for (int n = 0; n < 4; n++)
          acc[m][n] = __builtin_amdgcn_mfma_f32_16x16x32_bf16(af[m], bfr[n],
                                                              acc[m][n], 0, 0, 0);
    }
  }
#pragma unroll
  for (int n = 0; n < 4; n++) {
    int cg = bn + wn * 64 + n * 16 + lr;
    float bv = bias ? bias[cg] : 0.0f;
#pragma unroll
    for (int m = 0; m < 8; m++) {
#pragma unroll
      for (int rr = 0; rr < 4; rr++) {
        int rg = bm + wm * 128 + m * 16 + lg * 4 + rr;
        float v = acc[m][n][rr] + bv;
        if (act == 1) v = gelu_f(v);
        outB[cbase + (long)rg * ldc + cg] = (bf16)v;
      }
    }
  }
}

// ---------------- flash attention (R8 proven: QBLK=64) ---------------------
template <int WINDOWED>
__global__ __launch_bounds__(256) void k_flash(const bf16* __restrict__ Qg,
                                               const bf16* __restrict__ Kg,
                                               const bf16* __restrict__ Vtg,
                                               bf16* __restrict__ Og, int nkv) {
  __shared__ __align__(16) bf16 Qs[64 * 64];  // Q tile; after hoist: P buffer
  __shared__ __align__(16) bf16 Ks[2][64 * 64];
  __shared__ __align__(16) bf16 Vs[2][64 * 64];
  int flat = blockIdx.y * 32 + blockIdx.x;
  int flat2 = (flat & 7) * 128 + (flat >> 3);
  int i0 = (flat2 & 31) * 64;
  int bh = flat2 >> 5;
  int b = bh >> 4, h = bh & 15;
  int t = threadIdx.x, w = t >> 6, lane = t & 63;
  int lr = lane & 15, lg = lane >> 4;
  long qoff = ((long)b * Lc + i0) * Dc + h * DHc;
  long koff = ((long)b * nkv) * Dc + h * DHc;
  long vtoff = (long)bh * DHc * nkv;
  int o0 = w * 1024 + (lane << 4), o1 = o0 + 4096;
  int r0 = o0 >> 7, c0 = (o0 & 127) ^ ((r0 & 7) << 4);
  int r1 = o1 >> 7, c1 = (o1 & 127) ^ ((r1 & 7) << 4);
  int d0 = c0 >> 1, d1 = c1 >> 1;
  gload16(Qg + qoff + (long)r0 * Dc + d0, &Qs[w * 512]);
  gload16(Qg + qoff + (long)r1 * Dc + d1, &Qs[2048 + w * 512]);
  int kb0 = WINDOWED ? (i0 >= 64 ? i0 - 64 : 0) : 0;
  int nt = WINDOWED ? ((i0 - kb0) >> 6) + 1 : (nkv >> 6);
  auto stage = [&](int buf, int kbase) {
    gload16(Kg + koff + (long)(kbase + r0) * Dc + d0, &Ks[buf][w * 512]);
    gload16(Kg + koff + (long)(kbase + r1) * Dc + d1, &Ks[buf][2048 + w * 512]);
    gload16(Vtg + vtoff + (long)r0 * nkv + kbase + d0, &Vs[buf][w * 512]);
    gload16(Vtg + vtoff + (long)r1 * nkv + kbase + d1, &Vs[buf][2048 + w * 512]);
  };
  stage(0, kb0);
  WAIT_VM(4);  // Q complete
  RAW_BAR();
  SCHED_FENCE();
  bf16x8 bq[2];
#pragma unroll
  for (int ks = 0; ks < 2; ks++) {
    int rq = w * 16 + lr, cb = ks * 64 + lg * 16;
    bq[ks] = *(const bf16x8*)&Qs[((rq << 7) + (cb ^ ((rq & 7) << 4))) >> 1];
  }
  char* pbase = (char*)&Qs[w * 1024];  // per-wave-private P region
  float mrun = -1e30f, lrun = 0.f;     // windowed path state
  float mx_c = 0.0f;                   // cross path: per-q running max
  f32x4 oa[4] = {};
  f32x4 lacc = {};                     // cross path: denominator acc
  bf16x8 ones;
#pragma unroll
  for (int e = 0; e < 8; e++) ones[e] = (bf16)1.0f;
  float slopeL2 = WINDOWED ? exp2f(-0.5f * (float)(h + 1)) * 1.44269504f : 0.0f;
  int qabs = i0 + w * 16 + lr;
  int xr16 = (lr & 7) << 4;
  for (int tch = 0; tch < nt; tch++) {
    int cur = tch & 1;
    if (tch + 1 < nt) {
      stage(cur ^ 1, kb0 + (tch + 1) * 64);
      WAIT_VM(4);
    } else {
      WAIT_VM(0);
    }
    RAW_BAR();
    SCHED_FENCE();
    int kbase = kb0 + tch * 64;
    f32x4 st[4] = {};
    __builtin_amdgcn_s_setprio(1);
#pragma unroll
    for (int ks = 0; ks < 2; ks++) {
#pragma unroll
      for (int m = 0; m < 4; m++) {
        int rk = m * 16 + lr, cb = ks * 64 + lg * 16;
        bf16x8 ka = *(const bf16x8*)&Ks[cur][((rk << 7) + (cb ^ ((rk & 7) << 4))) >> 1];
        st[m] = __builtin_amdgcn_mfma_f32_16x16x32_bf16(ka, bq[ks], st[m], 0, 0, 0);
      }
    }
    __builtin_amdgcn_s_setprio(0);
    if (WINDOWED) {
      float sc[4][4];
#pragma unroll
      for (int m = 0; m < 4; m++)
#pragma unroll
        for (int rr = 0; rr < 4; rr++) {
          float v = st[m][rr];
          int kab = kbase + m * 16 + lg * 4 + rr;
          v += slopeL2 * (float)(kab - qabs);
          bool valid = (kab <= qabs) && (qabs - kab < 64);
          sc[m][rr] = valid ? v : -3.0e38f;
        }
      float pmax = sc[0][0];
#pragma unroll
      for (int m = 0; m < 4; m++)
#pragma unroll
        for (int rr = 0; rr < 4; rr++) pmax = fmaxf(pmax, sc[m][rr]);
      pmax = fmaxf(pmax, __shfl_xor(pmax, 16));
      pmax = fmaxf(pmax, __shfl_xor(pmax, 32));
      float mx = mrun;
      if (!__all(pmax - mrun <= 8.0f)) {
        mx = fmaxf(mrun, pmax);
        float corr = exp2f(mrun - mx);
        mrun = mx;
        lrun *= corr;
        float cq[4];
#pragma unroll
        for (int rr = 0; rr < 4; rr++) cq[rr] = __shfl(corr, lg * 4 + rr);
#pragma unroll
        for (int jd = 0; jd < 4; jd++) {
          oa[jd][0] *= cq[0]; oa[jd][1] *= cq[1];
          oa[jd][2] *= cq[2]; oa[jd][3] *= cq[3];
        }
      }
      float ps = 0.f;
#pragma unroll
      for (int m = 0; m < 4; m++) {
        float p0 = exp2f(sc[m][0] - mx);
        float p1 = exp2f(sc[m][1] - mx);
        float p2 = exp2f(sc[m][2] - mx);
        float p3 = exp2f(sc[m][3] - mx);
        ps += (p0 + p1) + (p2 + p3);
        bf16x4 pw; pw[0] = (bf16)p0; pw[1] = (bf16)p1;
        pw[2] = (bf16)p2; pw[3] = (bf16)p3;
        *(bf16x4*)(pbase + (lr << 7) + ((m * 32 + lg * 8) ^ xr16)) = pw;
      }
      lrun += ps;
      __builtin_amdgcn_s_setprio(1);
#pragma unroll
      for (int ks = 0; ks < 2; ks++) {
        bf16x8 pa = *(const bf16x8*)(pbase + (lr << 7) +
                                     ((ks * 64 + lg * 16) ^ xr16));
#pragma unroll
        for (int jd = 0; jd < 4; jd++) {
          int rv = jd * 16 + lr, cb = ks * 64 + lg * 16;
          bf16x8 vf = *(const bf16x8*)&Vs[cur][((rv << 7) + (cb ^ ((rv & 7) << 4))) >> 1];
          oa[jd] = __builtin_amdgcn_mfma_f32_16x16x32_bf16(pa, vf, oa[jd], 0, 0, 0);
        }
      }
      __builtin_amdgcn_s_setprio(0);
    } else {
      if (tch == 0) {
        float pmax = st[0][0];
#pragma unroll
        for (int m = 0; m < 4; m++)
#pragma unroll
          for (int rr = 0; rr < 4; rr++) pmax = fmaxf(pmax, st[m][rr]);
        pmax = fmaxf(pmax, __shfl_xor(pmax, 16));
        pmax = fmaxf(pmax, __shfl_xor(pmax, 32));
        mx_c = pmax;
      }
#pragma unroll
      for (int m = 0; m < 4; m++) {
        float p0 = exp2f(st[m][0] - mx_c);
        float p1 = exp2f(st[m][1] - mx_c);
        float p2 = exp2f(st[m][2] - mx_c);
        float p3 = exp2f(st[m][3] - mx_c);
        bf16x4 pw; pw[0] = (bf16)p0; pw[1] = (bf16)p1;
        pw[2] = (bf16)p2; pw[3] = (bf16)p3;
        *(bf16x4*)(pbase + (lr << 7) + ((m * 32 + lg * 8) ^ xr16)) = pw;
      }
      __builtin_amdgcn_s_setprio(1);
#pragma unroll
      for (int ks = 0; ks < 2; ks++) {
        bf16x8 pa = *(const bf16x8*)(pbase + (lr << 7) +
                                     ((ks * 64 + lg * 16) ^ xr16));
        lacc = __builtin_amdgcn_mfma_f32_16x16x32_bf16(pa, ones, lacc, 0, 0, 0);
#pragma unroll
        for (int jd = 0; jd < 4; jd++) {
          int rv = jd * 16 + lr, cb = ks * 64 + lg * 16;
          bf16x8 vf = *(const bf16x8*)&Vs[cur][((rv << 7) + (cb ^ ((rv & 7) << 4))) >> 1];
          oa[jd] = __builtin_amdgcn_mfma_f32_16x16x32_bf16(pa, vf, oa[jd], 0, 0, 0);
        }
      }
      __builtin_amdgcn_s_setprio(0);
      float lm = fmaxf(fmaxf(lacc[0], lacc[1]), fmaxf(lacc[2], lacc[3]));
      if (!__all(lm < 16777216.0f)) {
        const float cs = 2.3283064365386963e-10f;  // 2^-32
        mx_c += 32.0f;
#pragma unroll
        for (int jd = 0; jd < 4; jd++) {
          oa[jd][0] *= cs; oa[jd][1] *= cs;
          oa[jd][2] *= cs; oa[jd][3] *= cs;
        }
        lacc[0] *= cs; lacc[1] *= cs; lacc[2] *= cs; lacc[3] *= cs;
      }
    }
    WAIT_LGKM(0);
    SCHED_FENCE();
    RAW_BAR();
  }
  if (WINDOWED) {
    float ls = lrun + __shfl_xor(lrun, 16);
    ls += __shfl_xor(ls, 32);
    float inv = 1.0f / ls;
    float iq[4];
#pragma unroll
    for (int rr = 0; rr < 4; rr++) iq[rr] = __shfl(inv, lg * 4 + rr);
#pragma unroll
    for (int rr = 0; rr < 4; rr++) {
      int qo = i0 + w * 16 + lg * 4 + rr;
#pragma unroll
      for (int jd = 0; jd < 4; jd++)
        Og[((long)b * Lc + qo) * Dc + h * DHc + jd * 16 + lr] =
            (bf16)(oa[jd][rr] * iq[rr]);
    }
  } else {
#pragma unroll
    for (int rr = 0; rr < 4; rr++) {
      float inv = 1.0f / lacc[rr];
      int qo = i0 + w * 16 + lg * 4 + rr;
#pragma unroll
      for (int jd = 0; jd < 4; jd++)
        Og[((long)b * Lc + qo) * Dc + h * DHc + jd * 16 + lr] =
            (bf16)(oa[jd][rr] * inv);
    }
  }
}

// ---- fused: sum NS bf16 split-K slabs + bias + residual, then LayerNorm ----
template <int NS>
__global__ __launch_bounds__(256) void k_lnred(const bf16* __restrict__ psum,
                                               long slab,
                                               const float* __restrict__ bias,
                                               const float* __restrict__ addsrc,
                                               const float* __restrict__ g,
                                               const float* __restrict__ bb,
                                               float* __restrict__ outF,
                                               bf16* __restrict__ outB) {
  long row = blockIdx.x;
  int t = threadIdx.x; int lane = t & 63; int wid = t >> 6;
  __shared__ float red[8];
  bf16x4 v0 = *(const bf16x4*)(psum + row * Dc + t * 4);
  float v[4] = {(float)v0[0], (float)v0[1], (float)v0[2], (float)v0[3]};
#pragma unroll
  for (int s = 1; s < NS; s++) {
    bf16x4 u = *(const bf16x4*)(psum + s * slab + row * Dc + t * 4);
    v[0] += (float)u[0]; v[1] += (float)u[1];
    v[2] += (float)u[2]; v[3] += (float)u[3];
  }
  f32x4 bv = *(const f32x4*)(bias + t * 4);
  f32x4 av = *(const f32x4*)(addsrc + row * Dc + t * 4);
  v[0] += bv[0] + av[0]; v[1] += bv[1] + av[1];
  v[2] += bv[2] + av[2]; v[3] += bv[3] + av[3];
  float s = v[0] + v[1] + v[2] + v[3];
  float s2 = v[0] * v[0] + v[1] * v[1] + v[2] * v[2] + v[3] * v[3];
#pragma unroll
  for (int off = 1; off < 64; off <<= 1) {
    s += __shfl_xor(s, off);
    s2 += __shfl_xor(s2, off);
  }
  if (lane == 0) { red[wid] = s; red[4 + wid] = s2; }
  __syncthreads();
  s = red[0] + red[1] + red[2] + red[3];
  s2 = red[4] + red[5] + red[6] + red[7];
  float mu = s * (1.0f / Dc);
  float var = s2 * (1.0f / Dc) - mu * mu;
  float rs = rsqrtf(var + 1e-5f);
#pragma unroll
  for (int e = 0; e < 4; e++) {
    int c = t * 4 + e;
    float y = (v[e] - mu) * rs * g[c] + bb[c];
    if (outF) outF[row * Dc + c] = y;
    if (outB) outB[row * Dc + c] = (bf16)y;
  }
}

extern "C" void kernel_launch(void* const* d_in, const int* in_sizes, int n_in,
                              void* d_out, int out_size, void* d_ws,
                              size_t ws_size, hipStream_t stream) {
  (void)in_sizes; (void)n_in; (void)out_size; (void)ws_size;
  const float* x = (const float*)d_in[0];
  const float* mem = (const float*)d_in[1];
  const float* swq = (const float*)d_in[2];
  const float* swk = (const float*)d_in[3];
  const float* swv = (const float*)d_in[4];
  const float* swo = (const float*)d_in[5];
  const float* sbq = (const float*)d_in[6];
  const float* sbk = (const float*)d_in[7];
  const float* sbv = (const float*)d_in[8];
  const float* sbo = (const float*)d_in[9];
  const float* cwq = (const float*)d_in[10];
  const float* cwk = (const float*)d_in[11];
  const float* cwv = (const float*)d_in[12];
  const float* cwo = (const float*)d_in[13];
  const float* cbq = (const float*)d_in[14];
  const float* cbk = (const float*)d_in[15];
  const float* cbv = (const float*)d_in[16];
  const float* cbo = (const float*)d_in[17];
  const float* w1 = (const float*)d_in[18];
  const float* b1 = (const float*)d_in[19];
  const float* w2 = (const float*)d_in[20];
  const float* b2 = (const float*)d_in[21];
  const float* g1 = (const float*)d_in[22];
  const float* g2 = (const float*)d_in[23];
  const float* g3 = (const float*)d_in[24];
  const float* be1 = (const float*)d_in[25];
  const float* be2 = (const float*)d_in[26];
  const float* be3 = (const float*)d_in[27];
  float* out = (float*)d_out;

  char* ws = (char*)d_ws;
  size_t off = 0;
  auto alloc = [&](size_t bytes) -> char* {
    char* p = ws + off;
    off = (off + bytes + 255) & ~(size_t)255;
    return p;
  };

  const long BL = (long)Bc * Lc;  // 4096
  const long BM = (long)Bc * Mc;  // 4096
  const long DD = (long)Dc * Dc;
  const long SL = BL * Dc;  // one psum slab (elements)
  const float QSCL = 0.125f * 1.44269504f;  // fold 1/sqrt(DH)*log2e into Q

  bf16* wT0 = (bf16*)alloc((size_t)8 * DD * 2);
  bf16* w1T = (bf16*)alloc((size_t)FFc * Dc * 2);
  bf16* w2T = (bf16*)alloc((size_t)Dc * FFc * 2);
  bf16* xb = (bf16*)alloc((size_t)BL * Dc * 2);
  bf16* memb = (bf16*)alloc((size_t)BM * Dc * 2);
  bf16* x1b = (bf16*)alloc((size_t)BL * Dc * 2);
  bf16* x2b = (bf16*)alloc((size_t)BL * Dc * 2);
  bf16* qb = (bf16*)alloc((size_t)BL * Dc * 2);  // qb,kb,vb contiguous
  bf16* kb = (bf16*)alloc((size_t)BM * Dc * 2);
  bf16* vb = (bf16*)alloc((size_t)BM * Dc * 2);
  bf16* ob = (bf16*)alloc((size_t)BL * Dc * 2);
  bf16* vtS = (bf16*)alloc((size_t)Bc * Hc * DHc * Lc * 2);
  bf16* vtC = (bf16*)alloc((size_t)Bc * Hc * DHc * Mc * 2);
  float* x1f = (float*)alloc((size_t)BL * Dc * 4);
  float* x2f = (float*)alloc((size_t)BL * Dc * 4);
  bf16* ffh = (bf16*)alloc((size_t)BL * FFc * 2);
  bf16* psum = (bf16*)alloc((size_t)4 * SL * 2);  // 4 bf16 split-K slabs

  // ---- prep: weights -> bf16 [N,K] (8 DxD batched into one launch)
  Ptrs8 srcs;
  srcs.p[0] = swq; srcs.p[1] = swk; srcs.p[2] = swv; srcs.p[3] = swo;
  srcs.p[4] = cwq; srcs.p[5] = cwk; srcs.p[6] = cwv; srcs.p[7] = cwo;
  k_transpose_w8<<<dim3(Dc / 64, Dc / 64, 8), 256, 0, stream>>>(srcs, wT0);
  k_transpose_w<<<dim3(FFc / 64, Dc / 64), 256, 0, stream>>>(w1, w1T, Dc, FFc);
  k_transpose_w<<<dim3(Dc / 64, FFc / 64), 256, 0, stream>>>(w2, w2T, FFc, Dc);
  k_f2b<<<dim3((unsigned)(BL * Dc / 4 / 256)), 256, 0, stream>>>(x, xb, BL * Dc / 4);
  k_f2b<<<dim3((unsigned)(BM * Dc / 4 / 256)), 256, 0, stream>>>(mem, memb, BM * Dc / 4);

  // ---- self-attn QKV projections (z: q,k,v); Q prescaled
  k_gemm128<<<dim3(Dc / 128, BL / 128, 3), 256, 0, stream>>>(
      xb, xb, xb, Dc, wT0, DD, qb, Dc, SL, sbq, sbk, sbv, Dc, 0, QSCL);
  k_transpose_v<<<dim3(Lc / 64, Bc * Hc), 256, 0, stream>>>(vb, vtS, Lc);
  // ---- windowed causal self-attn + ALiBi
  k_flash<1><<<dim3(Lc / 64, Bc * Hc), 256, 0, stream>>>(qb, kb, vtS, ob, Lc);
  // ---- self O-proj (split-K=2) + fused bias/residual/LN
  k_gemmsk<<<dim3(Dc / 128, BL / 128, 2), 256, 0, stream>>>(
      ob, Dc, wT0 + 3 * DD, Dc, psum, SL, 512, Dc);
  k_lnred<2><<<dim3((unsigned)BL), 256, 0, stream>>>(psum, SL, sbo, x, g1, be1,
                                                     x1f, x1b);

  // ---- cross-attn Q,K,V projections (z: q,k,v); Q prescaled
  k_gemm128<<<dim3(Dc / 128, BM / 128, 3), 256, 0, stream>>>(
      x1b, memb, memb, Dc, wT0 + 4 * DD, DD, qb, Dc, SL, cbq, cbk, cbv, Dc, 0, QSCL);
  k_transpose_v<<<dim3(Mc / 64, Bc * Hc), 256, 0, stream>>>(vb, vtC, Mc);
  // ---- fused flash cross-attention (QBLK=64)
  k_flash<0><<<dim3(Lc / 64, Bc * Hc), 256, 0, stream>>>(qb, kb, vtC, ob, Mc);
  // ---- cross O-proj (split-K=2) + fused bias/residual/LN
  k_gemmsk<<<dim3(Dc / 128, BL / 128, 2), 256, 0, stream>>>(
      ob, Dc, wT0 + 7 * DD, Dc, psum, SL, 512, Dc);
  k_lnred<2><<<dim3((unsigned)BL), 256, 0, stream>>>(psum, SL, cbo, x1f, g2, be2,
                                                     x2f, x2b);

  // ---- FFN1: 256^2 tile, grid 16x16 = 256 blocks (1/CU), fused bias+GELU
  k_gemm256<<<dim3(FFc / 256, BL / 256, 1), 512, 0, stream>>>(
      x2b, Dc, w1T, Dc, ffh, FFc, 0, b1, Dc, 1);
  // ---- FFN2: 256^2 tile, split-K=4 -> grid 4x16x4 = 256 blocks, bf16 slabs
  k_gemm256<<<dim3(Dc / 256, BL / 256, 4), 512, 0, stream>>>(
      ffh, FFc, w2T, FFc, psum, Dc, SL, nullptr, 1024, 0);
  k_lnred<4><<<dim3((unsigned)BL), 256, 0, stream>>>(psum, SL, b2, x2f, g3, be3,
                                                     out, nullptr);
}

// Round 14
// 355.626 us; speedup vs baseline: 1.1933x; 1.1933x over previous
//
#include <hip/hip_runtime.h>
#include <hip/hip_bf16.h>
#include <math.h>

#define Bc 2
#define Lc 2048
#define Mc 2048
#define Dc 1024
#define Hc 16
#define FFc 4096
#define DHc 64

typedef __bf16 bf16;
typedef float f32x4 __attribute__((ext_vector_type(4)));
typedef __bf16 bf16x8 __attribute__((ext_vector_type(8)));
typedef __bf16 bf16x4 __attribute__((ext_vector_type(4)));
typedef __bf16 bf16x2 __attribute__((ext_vector_type(2)));

struct Ptrs8 { const float* p[8]; };

__device__ inline void gload16(const bf16* g, const bf16* lds_base) {
  __builtin_amdgcn_global_load_lds(
      (const __attribute__((address_space(1))) void*)g,
      (__attribute__((address_space(3))) void*)lds_base, 16, 0, 0);
}

#define WAIT_VM(n) asm volatile("s_waitcnt vmcnt(" #n ")" ::: "memory")
#define WAIT_LGKM(n) asm volatile("s_waitcnt lgkmcnt(" #n ")" ::: "memory")
#define RAW_BAR() __builtin_amdgcn_s_barrier()
#define SCHED_FENCE() __builtin_amdgcn_sched_barrier(0)

__device__ inline float gelu_f(float v) {
  float u = 0.7978845608f * (v + 0.044715f * v * v * v);
  float e = exp2f(u * 2.885390082f);  // exp(2u)
  float th = 1.0f - 2.0f / (e + 1.0f);
  return 0.5f * v * (1.0f + th);
}

// XCD-aware bijective remap of flat block id (requires nwg % 8 == 0)
__device__ inline int xcd_remap(int flat, int nwg) {
  int cpx = nwg >> 3;
  return (flat & 7) * cpx + (flat >> 3);
}

// ---------------- fp32 -> bf16 convert (vectorized) ----------------
__global__ __launch_bounds__(256) void k_f2b(const float* __restrict__ in,
                                             bf16* __restrict__ out, long n4) {
  long i = (long)blockIdx.x * 256 + threadIdx.x;
  if (i >= n4) return;
  f32x4 v = *(const f32x4*)(in + i * 4);
  bf16x4 o;
  o[0] = (bf16)v[0]; o[1] = (bf16)v[1]; o[2] = (bf16)v[2]; o[3] = (bf16)v[3];
  *(bf16x4*)(out + i * 4) = o;
}

// ------- batched weight transpose (8x DxD): out[z][n*K+k] = bf16(in_z[k*N+n])
__global__ __launch_bounds__(256) void k_transpose_w8(Ptrs8 srcs,
                                                      bf16* __restrict__ out) {
  __shared__ float tile[64][65];
  const float* in = srcs.p[blockIdx.z];
  bf16* o = out + (long)blockIdx.z * Dc * Dc;
  int n0 = blockIdx.x * 64, k0 = blockIdx.y * 64;
  int t = threadIdx.x;
  int tr = t >> 4, tc = (t & 15) * 4;
#pragma unroll
  for (int p = 0; p < 4; p++) {
    int r = p * 16 + tr;
    f32x4 v = *(const f32x4*)(in + (long)(k0 + r) * Dc + n0 + tc);
    tile[r][tc] = v[0]; tile[r][tc + 1] = v[1];
    tile[r][tc + 2] = v[2]; tile[r][tc + 3] = v[3];
  }
  __syncthreads();
#pragma unroll
  for (int p = 0; p < 4; p++) {
    int rn = p * 16 + tr;
    bf16x4 ov;
    ov[0] = (bf16)tile[tc + 0][rn]; ov[1] = (bf16)tile[tc + 1][rn];
    ov[2] = (bf16)tile[tc + 2][rn]; ov[3] = (bf16)tile[tc + 3][rn];
    *(bf16x4*)(o + (long)(n0 + rn) * Dc + k0 + tc) = ov;
  }
}

// ---------------- weight transpose+convert: out[n*K+k] = bf16(in[k*N+n]) ----
__global__ __launch_bounds__(256) void k_transpose_w(const float* __restrict__ in,
                                                     bf16* __restrict__ out,
                                                     int K, int N) {
  __shared__ float tile[64][65];
  int n0 = blockIdx.x * 64, k0 = blockIdx.y * 64;
  int t = threadIdx.x;
  int tr = t >> 4, tc = (t & 15) * 4;
#pragma unroll
  for (int p = 0; p < 4; p++) {
    int r = p * 16 + tr;
    f32x4 v = *(const f32x4*)(in + (long)(k0 + r) * N + n0 + tc);
    tile[r][tc] = v[0]; tile[r][tc + 1] = v[1];
    tile[r][tc + 2] = v[2]; tile[r][tc + 3] = v[3];
  }
  __syncthreads();
#pragma unroll
  for (int p = 0; p < 4; p++) {
    int rn = p * 16 + tr;
    bf16x4 o;
    o[0] = (bf16)tile[tc + 0][rn]; o[1] = (bf16)tile[tc + 1][rn];
    o[2] = (bf16)tile[tc + 2][rn]; o[3] = (bf16)tile[tc + 3][rn];
    *(bf16x4*)(out + (long)(n0 + rn) * K + k0 + tc) = o;
  }
}

// ---- V transpose: vt[(b*H+h)*DH+d][j] = vb[b][j][h*DH+d], j in [0,N) ------
__global__ __launch_bounds__(256) void k_transpose_v(const bf16* __restrict__ vb,
                                                     bf16* __restrict__ vt, int N) {
  __shared__ bf16 tile[64][72];
  int j0 = blockIdx.x * 64;
  int bh = blockIdx.y; int b = bh >> 4; int h = bh & 15;
  int t = threadIdx.x;
#pragma unroll
  for (int c = 0; c < 2; c++) {
    int id = t + c * 256;
    int r = id >> 3, c8 = (id & 7) * 8;
    *(bf16x8*)&tile[r][c8] =
        *(const bf16x8*)(vb + ((long)(b * N + j0 + r)) * Dc + h * DHc + c8);
  }
  __syncthreads();
#pragma unroll
  for (int c = 0; c < 2; c++) {
    int id = t + c * 256;
    int d = id >> 3, j8 = (id & 7) * 8;
    bf16x8 o;
#pragma unroll
    for (int e = 0; e < 8; e++) o[e] = tile[j8 + e][d];
    *(bf16x8*)(vt + ((long)bh * DHc + d) * N + j0 + j8) = o;
  }
}

// ------- 128x128 MFMA GEMM, BK=64, dbuf + counted vmcnt (R8/R9 proven) -----
__global__ __launch_bounds__(256) void k_gemm128(
    const bf16* __restrict__ A0, const bf16* __restrict__ A1,
    const bf16* __restrict__ A2, long lda,
    const bf16* __restrict__ B0, long bstride,
    bf16* __restrict__ outB, long ldc, long cstride,
    const float* __restrict__ bias0, const float* __restrict__ bias1,
    const float* __restrict__ bias2, int Kdim, int act, float scale0) {
  __shared__ __align__(16) bf16 As[2][128 * 64];
  __shared__ __align__(16) bf16 Bs[2][128 * 64];
  int gx = gridDim.x, gy = gridDim.y;
  int nwg = gx * gy * gridDim.z;
  int flat = (blockIdx.z * gy + blockIdx.y) * gx + blockIdx.x;
  int f2 = xcd_remap(flat, nwg);
  int bxi = f2 % gx; int tmp = f2 / gx;
  int byi = tmp % gy; int z = tmp / gy;
  const bf16* A = (z == 0) ? A0 : ((z == 1) ? A1 : A2);
  const bf16* Bt = B0 + (long)z * bstride;
  const float* bias = (z == 0) ? bias0 : ((z == 1) ? bias1 : bias2);
  float scl = (z == 0) ? scale0 : 1.0f;
  long cbase = (long)z * cstride;
  int bm = byi * 128, bn = bxi * 128;
  int t = threadIdx.x, w = t >> 6, lane = t & 63;
  int wm = w >> 1, wn = w & 1;
  int lr = lane & 15, lg = lane >> 4;
  int srow = lane >> 3;
  int scol = (((lane & 7) * 16) ^ ((lane >> 3) << 4)) >> 1;  // pre-swizzled src
  f32x4 acc[4][4] = {};
  int nk = Kdim >> 6;
  auto stage = [&](int buf, int kt2) {
    long k0 = (long)kt2 * 64;
#pragma unroll
    for (int i = 0; i < 4; i++) {
      int row = (i * 4 + w) * 8 + srow;
      gload16(A + (long)(bm + row) * lda + k0 + scol, &As[buf][(i * 4 + w) * 512]);
      gload16(Bt + (long)(bn + row) * Kdim + k0 + scol, &Bs[buf][(i * 4 + w) * 512]);
    }
  };
  stage(0, 0);
  if (nk > 1) stage(1, 1);
  for (int kt = 0; kt < nk; ++kt) {
    int cur = kt & 1;
    if (kt + 1 < nk) { WAIT_VM(8); } else { WAIT_VM(0); }
    RAW_BAR();
    SCHED_FENCE();
    const char* pa = (const char*)&As[cur][0];
    const char* pb = (const char*)&Bs[cur][0];
    int xr = (lr & 7) << 4;
    bf16x8 af[2][4], bfr[2][4];
#pragma unroll
    for (int m = 0; m < 4; m++) {
      int row = wm * 64 + m * 16 + lr;
      af[0][m] = *(const bf16x8*)(pa + (row << 7) + ((lg * 16) ^ xr));
    }
#pragma unroll
    for (int n = 0; n < 4; n++) {
      int row = wn * 64 + n * 16 + lr;
      bfr[0][n] = *(const bf16x8*)(pb + (row << 7) + ((lg * 16) ^ xr));
    }
    SCHED_FENCE();
#pragma unroll
    for (int m = 0; m < 4; m++) {
      int row = wm * 64 + m * 16 + lr;
      af[1][m] = *(const bf16x8*)(pa + (row << 7) + ((64 + lg * 16) ^ xr));
    }
#pragma unroll
    for (int n = 0; n < 4; n++) {
      int row = wn * 64 + n * 16 + lr;
      bfr[1][n] = *(const bf16x8*)(pb + (row << 7) + ((64 + lg * 16) ^ xr));
    }
    SCHED_FENCE();
    WAIT_LGKM(8);
    SCHED_FENCE();
#pragma unroll
    for (int m = 0; m < 4; m++)
#pragma unroll
      for (int n = 0; n < 4; n++)
        acc[m][n] = __builtin_amdgcn_mfma_f32_16x16x32_bf16(af[0][m], bfr[0][n],
                                                            acc[m][n], 0, 0, 0);
    WAIT_LGKM(0);
    SCHED_FENCE();
    RAW_BAR();
    if (kt + 2 < nk) stage(cur, kt + 2);
    SCHED_FENCE();
#pragma unroll
    for (int m = 0; m < 4; m++)
#pragma unroll
      for (int n = 0; n < 4; n++)
        acc[m][n] = __builtin_amdgcn_mfma_f32_16x16x32_bf16(af[1][m], bfr[1][n],
                                                            acc[m][n], 0, 0, 0);
  }
#pragma unroll
  for (int n = 0; n < 4; n++) {
    int cg = bn + wn * 64 + n * 16 + lr;
    float bv = bias ? bias[cg] : 0.0f;
#pragma unroll
    for (int m = 0; m < 4; m++) {
#pragma unroll
      for (int rr = 0; rr < 4; rr++) {
        int rg = bm + wm * 64 + m * 16 + lg * 4 + rr;
        float v = (acc[m][n][rr] + bv) * scl;
        if (act == 1) v = gelu_f(v);
        outB[cbase + (long)rg * ldc + cg] = (bf16)v;
      }
    }
  }
}

// ------- split-K GEMM -> bf16 partial slabs (R8/R9 proven) -----------------
__global__ __launch_bounds__(256) void k_gemmsk(
    const bf16* __restrict__ A, long lda,
    const bf16* __restrict__ Bt, int Kfull,
    bf16* __restrict__ psum, long slab, int Kchunk, int ldc) {
  __shared__ __align__(16) bf16 As[2][128 * 64];
  __shared__ __align__(16) bf16 Bs[2][128 * 64];
  int gx = gridDim.x, gy = gridDim.y;
  int nwg = gx * gy * gridDim.z;
  int flat = (blockIdx.z * gy + blockIdx.y) * gx + blockIdx.x;
  int f2 = xcd_remap(flat, nwg);
  int bxi = f2 % gx; int tmp = f2 / gx;
  int byi = tmp % gy; int z = tmp / gy;
  int bm = byi * 128, bn = bxi * 128;
  int t = threadIdx.x, w = t >> 6, lane = t & 63;
  int wm = w >> 1, wn = w & 1;
  int lr = lane & 15, lg = lane >> 4;
  int srow = lane >> 3;
  int scol = (((lane & 7) * 16) ^ ((lane >> 3) << 4)) >> 1;
  f32x4 acc[4][4] = {};
  int nk = Kchunk >> 6;
  long kstart = (long)z * Kchunk;
  auto stage = [&](int buf, int kt2) {
    long k0 = kstart + (long)kt2 * 64;
#pragma unroll
    for (int i = 0; i < 4; i++) {
      int row = (i * 4 + w) * 8 + srow;
      gload16(A + (long)(bm + row) * lda + k0 + scol, &As[buf][(i * 4 + w) * 512]);
      gload16(Bt + (long)(bn + row) * Kfull + k0 + scol, &Bs[buf][(i * 4 + w) * 512]);
    }
  };
  stage(0, 0);
  if (nk > 1) stage(1, 1);
  for (int kt = 0; kt < nk; ++kt) {
    int cur = kt & 1;
    if (kt + 1 < nk) { WAIT_VM(8); } else { WAIT_VM(0); }
    RAW_BAR();
    SCHED_FENCE();
    const char* pa = (const char*)&As[cur][0];
    const char* pb = (const char*)&Bs[cur][0];
    int xr = (lr & 7) << 4;
    bf16x8 af[2][4], bfr[2][4];
#pragma unroll
    for (int m = 0; m < 4; m++) {
      int row = wm * 64 + m * 16 + lr;
      af[0][m] = *(const bf16x8*)(pa + (row << 7) + ((lg * 16) ^ xr));
    }
#pragma unroll
    for (int n = 0; n < 4; n++) {
      int row = wn * 64 + n * 16 + lr;
      bfr[0][n] = *(const bf16x8*)(pb + (row << 7) + ((lg * 16) ^ xr));
    }
    SCHED_FENCE();
#pragma unroll
    for (int m = 0; m < 4; m++) {
      int row = wm * 64 + m * 16 + lr;
      af[1][m] = *(const bf16x8*)(pa + (row << 7) + ((64 + lg * 16) ^ xr));
    }
#pragma unroll
    for (int n = 0; n < 4; n++) {
      int row = wn * 64 + n * 16 + lr;
      bfr[1][n] = *(const bf16x8*)(pb + (row << 7) + ((64 + lg * 16) ^ xr));
    }
    SCHED_FENCE();
    WAIT_LGKM(8);
    SCHED_FENCE();
#pragma unroll
    for (int m = 0; m < 4; m++)
#pragma unroll
      for (int n = 0; n < 4; n++)
        acc[m][n] = __builtin_amdgcn_mfma_f32_16x16x32_bf16(af[0][m], bfr[0][n],
                                                            acc[m][n], 0, 0, 0);
    WAIT_LGKM(0);
    SCHED_FENCE();
    RAW_BAR();
    if (kt + 2 < nk) stage(cur, kt + 2);
    SCHED_FENCE();
#pragma unroll
    for (int m = 0; m < 4; m++)
#pragma unroll
      for (int n = 0; n < 4; n++)
        acc[m][n] = __builtin_amdgcn_mfma_f32_16x16x32_bf16(af[1][m], bfr[1][n],
                                                            acc[m][n], 0, 0, 0);
  }
  bf16* po = psum + (long)z * slab;
#pragma unroll
  for (int n = 0; n < 4; n++) {
    int cg = bn + wn * 64 + n * 16 + lr;
#pragma unroll
    for (int m = 0; m < 4; m++) {
#pragma unroll
      for (int rr = 0; rr < 4; rr++) {
        int rg = bm + wm * 64 + m * 16 + lg * 4 + rr;
        po[(long)rg * ldc + cg] = (bf16)acc[m][n][rr];
      }
    }
  }
}

// ---------------- flash attention (R9-measured best: QBLK=64) --------------
// cross (WINDOWED=0): chunk0-max, ones-MFMA denominator, overflow guard.
// self (WINDOWED=1): defer-max online softmax.
template <int WINDOWED>
__global__ __launch_bounds__(256) void k_flash(const bf16* __restrict__ Qg,
                                               const bf16* __restrict__ Kg,
                                               const bf16* __restrict__ Vtg,
                                               bf16* __restrict__ Og, int nkv) {
  __shared__ __align__(16) bf16 Qs[64 * 64];  // Q tile; after hoist: P buffer
  __shared__ __align__(16) bf16 Ks[2][64 * 64];
  __shared__ __align__(16) bf16 Vs[2][64 * 64];
  int flat = blockIdx.y * 32 + blockIdx.x;
  int flat2 = (flat & 7) * 128 + (flat >> 3);
  int i0 = (flat2 & 31) * 64;
  int bh = flat2 >> 5;
  int b = bh >> 4, h = bh & 15;
  int t = threadIdx.x, w = t >> 6, lane = t & 63;
  int lr = lane & 15, lg = lane >> 4;
  long qoff = ((long)b * Lc + i0) * Dc + h * DHc;
  long koff = ((long)b * nkv) * Dc + h * DHc;
  long vtoff = (long)bh * DHc * nkv;
  int o0 = w * 1024 + (lane << 4), o1 = o0 + 4096;
  int r0 = o0 >> 7, c0 = (o0 & 127) ^ ((r0 & 7) << 4);
  int r1 = o1 >> 7, c1 = (o1 & 127) ^ ((r1 & 7) << 4);
  int d0 = c0 >> 1, d1 = c1 >> 1;
  gload16(Qg + qoff + (long)r0 * Dc + d0, &Qs[w * 512]);
  gload16(Qg + qoff + (long)r1 * Dc + d1, &Qs[2048 + w * 512]);
  int kb0 = WINDOWED ? (i0 >= 64 ? i0 - 64 : 0) : 0;
  int nt = WINDOWED ? ((i0 - kb0) >> 6) + 1 : (nkv >> 6);
  auto stage = [&](int buf, int kbase) {
    gload16(Kg + koff + (long)(kbase + r0) * Dc + d0, &Ks[buf][w * 512]);
    gload16(Kg + koff + (long)(kbase + r1) * Dc + d1, &Ks[buf][2048 + w * 512]);
    gload16(Vtg + vtoff + (long)r0 * nkv + kbase + d0, &Vs[buf][w * 512]);
    gload16(Vtg + vtoff + (long)r1 * nkv + kbase + d1, &Vs[buf][2048 + w * 512]);
  };
  stage(0, kb0);
  WAIT_VM(4);  // Q complete
  RAW_BAR();
  SCHED_FENCE();
  bf16x8 bq[2];
#pragma unroll
  for (int ks = 0; ks < 2; ks++) {
    int rq = w * 16 + lr, cb = ks * 64 + lg * 16;
    bq[ks] = *(const bf16x8*)&Qs[((rq << 7) + (cb ^ ((rq & 7) << 4))) >> 1];
  }
  char* pbase = (char*)&Qs[w * 1024];  // per-wave-private P region
  float mrun = -1e30f, lrun = 0.f;     // windowed path state
  float mx_c = 0.0f;                   // cross path: per-q running max
  f32x4 oa[4] = {};
  f32x4 lacc = {};                     // cross path: denominator acc
  bf16x8 ones;
#pragma unroll
  for (int e = 0; e < 8; e++) ones[e] = (bf16)1.0f;
  float slopeL2 = WINDOWED ? exp2f(-0.5f * (float)(h + 1)) * 1.44269504f : 0.0f;
  int qabs = i0 + w * 16 + lr;
  int xr16 = (lr & 7) << 4;
  for (int tch = 0; tch < nt; tch++) {
    int cur = tch & 1;
    if (tch + 1 < nt) {
      stage(cur ^ 1, kb0 + (tch + 1) * 64);
      WAIT_VM(4);
    } else {
      WAIT_VM(0);
    }
    RAW_BAR();
    SCHED_FENCE();
    int kbase = kb0 + tch * 64;
    f32x4 st[4] = {};
    __builtin_amdgcn_s_setprio(1);
#pragma unroll
    for (int ks = 0; ks < 2; ks++) {
#pragma unroll
      for (int m = 0; m < 4; m++) {
        int rk = m * 16 + lr, cb = ks * 64 + lg * 16;
        bf16x8 ka = *(const bf16x8*)&Ks[cur][((rk << 7) + (cb ^ ((rk & 7) << 4))) >> 1];
        st[m] = __builtin_amdgcn_mfma_f32_16x16x32_bf16(ka, bq[ks], st[m], 0, 0, 0);
      }
    }
    __builtin_amdgcn_s_setprio(0);
    if (WINDOWED) {
      float sc[4][4];
#pragma unroll
      for (int m = 0; m < 4; m++)
#pragma unroll
        for (int rr = 0; rr < 4; rr++) {
          float v = st[m][rr];
          int kab = kbase + m * 16 + lg * 4 + rr;
          v += slopeL2 * (float)(kab - qabs);
          bool valid = (kab <= qabs) && (qabs - kab < 64);
          sc[m][rr] = valid ? v : -3.0e38f;
        }
      float pmax = sc[0][0];
#pragma unroll
      for (int m = 0; m < 4; m++)
#pragma unroll
        for (int rr = 0; rr < 4; rr++) pmax = fmaxf(pmax, sc[m][rr]);
      pmax = fmaxf(pmax, __shfl_xor(pmax, 16));
      pmax = fmaxf(pmax, __shfl_xor(pmax, 32));
      float mx = mrun;
      if (!__all(pmax - mrun <= 8.0f)) {
        mx = fmaxf(mrun, pmax);
        float corr = exp2f(mrun - mx);
        mrun = mx;
        lrun *= corr;
        float cq[4];
#pragma unroll
        for (int rr = 0; rr < 4; rr++) cq[rr] = __shfl(corr, lg * 4 + rr);
#pragma unroll
        for (int jd = 0; jd < 4; jd++) {
          oa[jd][0] *= cq[0]; oa[jd][1] *= cq[1];
          oa[jd][2] *= cq[2]; oa[jd][3] *= cq[3];
        }
      }
      float ps = 0.f;
#pragma unroll
      for (int m = 0; m < 4; m++) {
        float p0 = exp2f(sc[m][0] - mx);
        float p1 = exp2f(sc[m][1] - mx);
        float p2 = exp2f(sc[m][2] - mx);
        float p3 = exp2f(sc[m][3] - mx);
        ps += (p0 + p1) + (p2 + p3);
        bf16x4 pw; pw[0] = (bf16)p0; pw[1] = (bf16)p1;
        pw[2] = (bf16)p2; pw[3] = (bf16)p3;
        *(bf16x4*)(pbase + (lr << 7) + ((m * 32 + lg * 8) ^ xr16)) = pw;
      }
      lrun += ps;
      __builtin_amdgcn_s_setprio(1);
#pragma unroll
      for (int ks = 0; ks < 2; ks++) {
        bf16x8 pa = *(const bf16x8*)(pbase + (lr << 7) +
                                     ((ks * 64 + lg * 16) ^ xr16));
#pragma unroll
        for (int jd = 0; jd < 4; jd++) {
          int rv = jd * 16 + lr, cb = ks * 64 + lg * 16;
          bf16x8 vf = *(const bf16x8*)&Vs[cur][((rv << 7) + (cb ^ ((rv & 7) << 4))) >> 1];
          oa[jd] = __builtin_amdgcn_mfma_f32_16x16x32_bf16(pa, vf, oa[jd], 0, 0, 0);
        }
      }
      __builtin_amdgcn_s_setprio(0);
    } else {
      if (tch == 0) {
        float pmax = st[0][0];
#pragma unroll
        for (int m = 0; m < 4; m++)
#pragma unroll
          for (int rr = 0; rr < 4; rr++) pmax = fmaxf(pmax, st[m][rr]);
        pmax = fmaxf(pmax, __shfl_xor(pmax, 16));
        pmax = fmaxf(pmax, __shfl_xor(pmax, 32));
        mx_c = pmax;
      }
#pragma unroll
      for (int m = 0; m < 4; m++) {
        float p0 = exp2f(st[m][0] - mx_c);
        float p1 = exp2f(st[m][1] - mx_c);
        float p2 = exp2f(st[m][2] - mx_c);
        float p3 = exp2f(st[m][3] - mx_c);
        bf16x4 pw; pw[0] = (bf16)p0; pw[1] = (bf16)p1;
        pw[2] = (bf16)p2; pw[3] = (bf16)p3;
        *(bf16x4*)(pbase + (lr << 7) + ((m * 32 + lg * 8) ^ xr16)) = pw;
      }
      __builtin_amdgcn_s_setprio(1);
#pragma unroll
      for (int ks = 0; ks < 2; ks++) {
        bf16x8 pa = *(const bf16x8*)(pbase + (lr << 7) +
                                     ((ks * 64 + lg * 16) ^ xr16));
        lacc = __builtin_amdgcn_mfma_f32_16x16x32_bf16(pa, ones, lacc, 0, 0, 0);
#pragma unroll
        for (int jd = 0; jd < 4; jd++) {
          int rv = jd * 16 + lr, cb = ks * 64 + lg * 16;
          bf16x8 vf = *(const bf16x8*)&Vs[cur][((rv << 7) + (cb ^ ((rv & 7) << 4))) >> 1];
          oa[jd] = __builtin_amdgcn_mfma_f32_16x16x32_bf16(pa, vf, oa[jd], 0, 0, 0);
        }
      }
      __builtin_amdgcn_s_setprio(0);
      float lm = fmaxf(fmaxf(lacc[0], lacc[1]), fmaxf(lacc[2], lacc[3]));
      if (!__all(lm < 16777216.0f)) {
        const float cs = 2.3283064365386963e-10f;  // 2^-32
        mx_c += 32.0f;
#pragma unroll
        for (int jd = 0; jd < 4; jd++) {
          oa[jd][0] *= cs; oa[jd][1] *= cs;
          oa[jd][2] *= cs; oa[jd][3] *= cs;
        }
        lacc[0] *= cs; lacc[1] *= cs; lacc[2] *= cs; lacc[3] *= cs;
      }
    }
    WAIT_LGKM(0);
    SCHED_FENCE();
    RAW_BAR();
  }
  if (WINDOWED) {
    float ls = lrun + __shfl_xor(lrun, 16);
    ls += __shfl_xor(ls, 32);
    float inv = 1.0f / ls;
    float iq[4];
#pragma unroll
    for (int rr = 0; rr < 4; rr++) iq[rr] = __shfl(inv, lg * 4 + rr);
#pragma unroll
    for (int rr = 0; rr < 4; rr++) {
      int qo = i0 + w * 16 + lg * 4 + rr;
#pragma unroll
      for (int jd = 0; jd < 4; jd++)
        Og[((long)b * Lc + qo) * Dc + h * DHc + jd * 16 + lr] =
            (bf16)(oa[jd][rr] * iq[rr]);
    }
  } else {
#pragma unroll
    for (int rr = 0; rr < 4; rr++) {
      float inv = 1.0f / lacc[rr];
      int qo = i0 + w * 16 + lg * 4 + rr;
#pragma unroll
      for (int jd = 0; jd < 4; jd++)
        Og[((long)b * Lc + qo) * Dc + h * DHc + jd * 16 + lr] =
            (bf16)(oa[jd][rr] * inv);
    }
  }
}

// ---- fused: sum NS bf16 split-K slabs + bias + residual, then LayerNorm ----
template <int NS>
__global__ __launch_bounds__(256) void k_lnred(const bf16* __restrict__ psum,
                                               long slab,
                                               const float* __restrict__ bias,
                                               const float* __restrict__ addsrc,
                                               const float* __restrict__ g,
                                               const float* __restrict__ bb,
                                               float* __restrict__ outF,
                                               bf16* __restrict__ outB) {
  long row = blockIdx.x;
  int t = threadIdx.x; int lane = t & 63; int wid = t >> 6;
  __shared__ float red[8];
  bf16x4 v0 = *(const bf16x4*)(psum + row * Dc + t * 4);
  float v[4] = {(float)v0[0], (float)v0[1], (float)v0[2], (float)v0[3]};
#pragma unroll
  for (int s = 1; s < NS; s++) {
    bf16x4 u = *(const bf16x4*)(psum + s * slab + row * Dc + t * 4);
    v[0] += (float)u[0]; v[1] += (float)u[1];
    v[2] += (float)u[2]; v[3] += (float)u[3];
  }
  f32x4 bv = *(const f32x4*)(bias + t * 4);
  f32x4 av = *(const f32x4*)(addsrc + row * Dc + t * 4);
  v[0] += bv[0] + av[0]; v[1] += bv[1] + av[1];
  v[2] += bv[2] + av[2]; v[3] += bv[3] + av[3];
  float s = v[0] + v[1] + v[2] + v[3];
  float s2 = v[0] * v[0] + v[1] * v[1] + v[2] * v[2] + v[3] * v[3];
#pragma unroll
  for (int off = 1; off < 64; off <<= 1) {
    s += __shfl_xor(s, off);
    s2 += __shfl_xor(s2, off);
  }
  if (lane == 0) { red[wid] = s; red[4 + wid] = s2; }
  __syncthreads();
  s = red[0] + red[1] + red[2] + red[3];
  s2 = red[4] + red[5] + red[6] + red[7];
  float mu = s * (1.0f / Dc);
  float var = s2 * (1.0f / Dc) - mu * mu;
  float rs = rsqrtf(var + 1e-5f);
#pragma unroll
  for (int e = 0; e < 4; e++) {
    int c = t * 4 + e;
    float y = (v[e] - mu) * rs * g[c] + bb[c];
    if (outF) outF[row * Dc + c] = y;
    if (outB) outB[row * Dc + c] = (bf16)y;
  }
}

extern "C" void kernel_launch(void* const* d_in, const int* in_sizes, int n_in,
                              void* d_out, int out_size, void* d_ws,
                              size_t ws_size, hipStream_t stream) {
  (void)in_sizes; (void)n_in; (void)out_size; (void)ws_size;
  const float* x = (const float*)d_in[0];
  const float* mem = (const float*)d_in[1];
  const float* swq = (const float*)d_in[2];
  const float* swk = (const float*)d_in[3];
  const float* swv = (const float*)d_in[4];
  const float* swo = (const float*)d_in[5];
  const float* sbq = (const float*)d_in[6];
  const float* sbk = (const float*)d_in[7];
  const float* sbv = (const float*)d_in[8];
  const float* sbo = (const float*)d_in[9];
  const float* cwq = (const float*)d_in[10];
  const float* cwk = (const float*)d_in[11];
  const float* cwv = (const float*)d_in[12];
  const float* cwo = (const float*)d_in[13];
  const float* cbq = (const float*)d_in[14];
  const float* cbk = (const float*)d_in[15];
  const float* cbv = (const float*)d_in[16];
  const float* cbo = (const float*)d_in[17];
  const float* w1 = (const float*)d_in[18];
  const float* b1 = (const float*)d_in[19];
  const float* w2 = (const float*)d_in[20];
  const float* b2 = (const float*)d_in[21];
  const float* g1 = (const float*)d_in[22];
  const float* g2 = (const float*)d_in[23];
  const float* g3 = (const float*)d_in[24];
  const float* be1 = (const float*)d_in[25];
  const float* be2 = (const float*)d_in[26];
  const float* be3 = (const float*)d_in[27];
  float* out = (float*)d_out;

  char* ws = (char*)d_ws;
  size_t off = 0;
  auto alloc = [&](size_t bytes) -> char* {
    char* p = ws + off;
    off = (off + bytes + 255) & ~(size_t)255;
    return p;
  };

  const long BL = (long)Bc * Lc;  // 4096
  const long BM = (long)Bc * Mc;  // 4096
  const long DD = (long)Dc * Dc;
  const long SL = BL * Dc;  // one psum slab (elements)
  const float QSCL = 0.125f * 1.44269504f;  // fold 1/sqrt(DH)*log2e into Q

  bf16* wT0 = (bf16*)alloc((size_t)8 * DD * 2);
  bf16* w1T = (bf16*)alloc((size_t)FFc * Dc * 2);
  bf16* w2T = (bf16*)alloc((size_t)Dc * FFc * 2);
  bf16* xb = (bf16*)alloc((size_t)BL * Dc * 2);
  bf16* memb = (bf16*)alloc((size_t)BM * Dc * 2);
  bf16* x1b = (bf16*)alloc((size_t)BL * Dc * 2);
  bf16* x2b = (bf16*)alloc((size_t)BL * Dc * 2);
  bf16* qb = (bf16*)alloc((size_t)BL * Dc * 2);  // qb,kb,vb contiguous
  bf16* kb = (bf16*)alloc((size_t)BM * Dc * 2);
  bf16* vb = (bf16*)alloc((size_t)BM * Dc * 2);
  bf16* ob = (bf16*)alloc((size_t)BL * Dc * 2);
  bf16* vtS = (bf16*)alloc((size_t)Bc * Hc * DHc * Lc * 2);
  bf16* vtC = (bf16*)alloc((size_t)Bc * Hc * DHc * Mc * 2);
  float* x1f = (float*)alloc((size_t)BL * Dc * 4);
  float* x2f = (float*)alloc((size_t)BL * Dc * 4);
  bf16* ffh = (bf16*)alloc((size_t)BL * FFc * 2);
  bf16* psum = (bf16*)alloc((size_t)4 * SL * 2);  // split-K slabs

  // ---- prep: weights -> bf16 [N,K] (8 DxD batched into one launch)
  Ptrs8 srcs;
  srcs.p[0] = swq; srcs.p[1] = swk; srcs.p[2] = swv; srcs.p[3] = swo;
  srcs.p[4] = cwq; srcs.p[5] = cwk; srcs.p[6] = cwv; srcs.p[7] = cwo;
  k_transpose_w8<<<dim3(Dc / 64, Dc / 64, 8), 256, 0, stream>>>(srcs, wT0);
  k_transpose_w<<<dim3(FFc / 64, Dc / 64), 256, 0, stream>>>(w1, w1T, Dc, FFc);
  k_transpose_w<<<dim3(Dc / 64, FFc / 64), 256, 0, stream>>>(w2, w2T, FFc, Dc);
  k_f2b<<<dim3((unsigned)(BL * Dc / 4 / 256)), 256, 0, stream>>>(x, xb, BL * Dc / 4);
  k_f2b<<<dim3((unsigned)(BM * Dc / 4 / 256)), 256, 0, stream>>>(mem, memb, BM * Dc / 4);

  // ---- self-attn QKV projections (z: q,k,v); Q prescaled
  k_gemm128<<<dim3(Dc / 128, BL / 128, 3), 256, 0, stream>>>(
      xb, xb, xb, Dc, wT0, DD, qb, Dc, SL, sbq, sbk, sbv, Dc, 0, QSCL);
  k_transpose_v<<<dim3(Lc / 64, Bc * Hc), 256, 0, stream>>>(vb, vtS, Lc);
  // ---- windowed causal self-attn + ALiBi
  k_flash<1><<<dim3(Lc / 64, Bc * Hc), 256, 0, stream>>>(qb, kb, vtS, ob, Lc);
  // ---- self O-proj (split-K=2) + fused bias/residual/LN
  k_gemmsk<<<dim3(Dc / 128, BL / 128, 2), 256, 0, stream>>>(
      ob, Dc, wT0 + 3 * DD, Dc, psum, SL, 512, Dc);
  k_lnred<2><<<dim3((unsigned)BL), 256, 0, stream>>>(psum, SL, sbo, x, g1, be1,
                                                     x1f, x1b);

  // ---- cross-attn Q,K,V projections (z: q,k,v); Q prescaled
  k_gemm128<<<dim3(Dc / 128, BM / 128, 3), 256, 0, stream>>>(
      x1b, memb, memb, Dc, wT0 + 4 * DD, DD, qb, Dc, SL, cbq, cbk, cbv, Dc, 0, QSCL);
  k_transpose_v<<<dim3(Mc / 64, Bc * Hc), 256, 0, stream>>>(vb, vtC, Mc);
  // ---- fused flash cross-attention (QBLK=64)
  k_flash<0><<<dim3(Lc / 64, Bc * Hc), 256, 0, stream>>>(qb, kb, vtC, ob, Mc);
  // ---- cross O-proj (split-K=2) + fused bias/residual/LN
  k_gemmsk<<<dim3(Dc / 128, BL / 128, 2), 256, 0, stream>>>(
      ob, Dc, wT0 + 7 * DD, Dc, psum, SL, 512, Dc);
  k_lnred<2><<<dim3((unsigned)BL), 256, 0, stream>>>(psum, SL, cbo, x1f, g2, be2,
                                                     x2f, x2b);

  // ---- FFN
  k_gemm128<<<dim3(FFc / 128, BL / 128, 1), 256, 0, stream>>>(
      x2b, x2b, x2b, Dc, w1T, 0, ffh, FFc, 0, b1, b1, b1, Dc, 1, 1.0f);
  // FFN2: split-K=2 (Kchunk=2048) -> grid 512, half psum traffic vs sk4
  k_gemmsk<<<dim3(Dc / 128, BL / 128, 2), 256, 0, stream>>>(
      ffh, FFc, w2T, FFc, psum, SL, 2048, Dc);
  k_lnred<2><<<dim3((unsigned)BL), 256, 0, stream>>>(psum, SL, b2, x2f, g3, be3,
                                                     out, nullptr);
}